// Round 2
// baseline (3415.283 us; speedup 1.0000x reference)
//
#include <hip/hip_runtime.h>

#define BB 8
#define NPTS 2048
#define DD 256
#define CCH 128
#define NCLASS 50

// ---------- eA / eB: exp(i * pts@A), exp(i * pts@B) ----------
__global__ __launch_bounds__(256) void ek_kernel(
    const float* __restrict__ xyz, const float* __restrict__ A,
    const float* __restrict__ Bm, float2* __restrict__ EA, float2* __restrict__ EB)
{
  size_t idx = (size_t)blockIdx.x*256 + threadIdx.x;
  int d = (int)(idx & (DD-1));
  size_t bn = idx >> 8;
  int n = (int)(bn & (NPTS-1));
  int b = (int)(bn >> 11);
  float p0 = xyz[((size_t)b*3+0)*NPTS+n];
  float p1 = xyz[((size_t)b*3+1)*NPTS+n];
  float p2 = xyz[((size_t)b*3+2)*NPTS+n];
  float phA = p0*A[d] + p1*A[DD+d] + p2*A[2*DD+d];
  float phB = p0*Bm[d] + p1*Bm[DD+d] + p2*Bm[2*DD+d];
  float s, c;
  sincosf(phA, &s, &c); EA[idx] = make_float2(c, s);
  sincosf(phB, &s, &c); EB[idx] = make_float2(c, s);
}

// ---------- inner[b,d,e] = sum_n conj(eB[b,n,d]) * eA[b,n,e] ----------
__global__ __launch_bounds__(256) void inner_kernel(
    const float2* __restrict__ EB, const float2* __restrict__ EA, float2* __restrict__ OUT)
{
  int b = blockIdx.z;
  int d0 = blockIdx.y*32, e0 = blockIdx.x*32;
  const float2* eb = EB + (size_t)b*NPTS*DD;
  const float2* ea = EA + (size_t)b*NPTS*DD;
  __shared__ float2 sB[32][33], sA[32][33];
  int tid = threadIdx.y*16 + threadIdx.x;
  int lx = tid & 31, lk = tid >> 5;
  float ar[2][2] = {{0.f,0.f},{0.f,0.f}}, ai[2][2] = {{0.f,0.f},{0.f,0.f}};
  for (int n0 = 0; n0 < NPTS; n0 += 32) {
    #pragma unroll
    for (int i = 0; i < 4; i++) {
      int kk = lk + i*8;
      sB[kk][lx] = eb[(size_t)(n0+kk)*DD + d0+lx];
      sA[kk][lx] = ea[(size_t)(n0+kk)*DD + e0+lx];
    }
    __syncthreads();
    #pragma unroll
    for (int kk = 0; kk < 32; kk++) {
      float2 b0 = sB[kk][threadIdx.y], b1 = sB[kk][threadIdx.y+16];
      float2 a0 = sA[kk][threadIdx.x], a1 = sA[kk][threadIdx.x+16];
      ar[0][0] += b0.x*a0.x + b0.y*a0.y;  ai[0][0] += b0.x*a0.y - b0.y*a0.x;
      ar[0][1] += b0.x*a1.x + b0.y*a1.y;  ai[0][1] += b0.x*a1.y - b0.y*a1.x;
      ar[1][0] += b1.x*a0.x + b1.y*a0.y;  ai[1][0] += b1.x*a0.y - b1.y*a0.x;
      ar[1][1] += b1.x*a1.x + b1.y*a1.y;  ai[1][1] += b1.x*a1.y - b1.y*a1.x;
    }
    __syncthreads();
  }
  #pragma unroll
  for (int i = 0; i < 2; i++)
    #pragma unroll
    for (int j = 0; j < 2; j++) {
      int d = d0 + threadIdx.y + i*16, e = e0 + threadIdx.x + j*16;
      OUT[((size_t)b*DD + d)*DD + e] = make_float2(ar[i][j], ai[i][j]);
    }
}

// ---------- G[b,n,e] = sum_d eB[b,n,d] * inner[b,d,e] ----------
__global__ __launch_bounds__(256) void g_kernel(
    const float2* __restrict__ EB, const float2* __restrict__ INN, float2* __restrict__ G)
{
  int b = blockIdx.z;
  int n0 = blockIdx.y*32, e0 = blockIdx.x*32;
  const float2* eb = EB + (size_t)b*NPTS*DD;
  const float2* inn = INN + (size_t)b*DD*DD;
  __shared__ float2 sE[32][33], sI[32][33];   // sE[dd][nn], sI[dd][ee]
  int tid = threadIdx.y*16 + threadIdx.x;
  int lx = tid & 31, lr = tid >> 5;
  float gr[2][2] = {{0.f,0.f},{0.f,0.f}}, gi[2][2] = {{0.f,0.f},{0.f,0.f}};
  for (int d0 = 0; d0 < DD; d0 += 32) {
    #pragma unroll
    for (int i = 0; i < 4; i++) {
      int rr = lr + i*8;
      sE[lx][rr] = eb[(size_t)(n0+rr)*DD + d0+lx];
      sI[rr][lx] = inn[(size_t)(d0+rr)*DD + e0+lx];
    }
    __syncthreads();
    #pragma unroll
    for (int kk = 0; kk < 32; kk++) {
      float2 e0v = sE[kk][threadIdx.y], e1v = sE[kk][threadIdx.y+16];
      float2 w0 = sI[kk][threadIdx.x], w1 = sI[kk][threadIdx.x+16];
      gr[0][0] += e0v.x*w0.x - e0v.y*w0.y;  gi[0][0] += e0v.x*w0.y + e0v.y*w0.x;
      gr[0][1] += e0v.x*w1.x - e0v.y*w1.y;  gi[0][1] += e0v.x*w1.y + e0v.y*w1.x;
      gr[1][0] += e1v.x*w0.x - e1v.y*w0.y;  gi[1][0] += e1v.x*w0.y + e1v.y*w0.x;
      gr[1][1] += e1v.x*w1.x - e1v.y*w1.y;  gi[1][1] += e1v.x*w1.y + e1v.y*w1.x;
    }
    __syncthreads();
  }
  #pragma unroll
  for (int i = 0; i < 2; i++)
    #pragma unroll
    for (int j = 0; j < 2; j++) {
      int n = n0 + threadIdx.y + i*16, e = e0 + threadIdx.x + j*16;
      G[((size_t)b*NPTS + n)*DD + e] = make_float2(gr[i][j], gi[i][j]);
    }
}

// ---------- normalize each row of G to norm sqrt(D) ----------
__global__ __launch_bounds__(256) void gnorm_kernel(float2* __restrict__ G)
{
  size_t row = blockIdx.x;
  float2* p = G + row*DD;
  int tid = threadIdx.x;
  float2 v = p[tid];
  __shared__ float red[256];
  red[tid] = v.x*v.x + v.y*v.y;
  __syncthreads();
  for (int w = 128; w > 0; w >>= 1) { if (tid < w) red[tid] += red[tid+w]; __syncthreads(); }
  float sc = 16.f * rsqrtf(red[0]);   // sqrt(256) / norm
  p[tid] = make_float2(v.x*sc, v.y*sc);
}

// ---------- complex linear: OUT[m,o] = IN[m,:] . (Wr[o,:] + i Wi[o,:]) + (br-bi) + i(br+bi) ----------
__global__ __launch_bounds__(256) void clinear_kernel(
    const float2* __restrict__ IN, const float* __restrict__ Wr, const float* __restrict__ Wi,
    const float* __restrict__ br, const float* __restrict__ bi,
    float2* __restrict__ OUT, int do_relu)
{
  int m0 = blockIdx.y*32, o0 = blockIdx.x*32;
  __shared__ float2 sX[32][33], sW[32][33];
  int tid = threadIdx.y*16 + threadIdx.x;
  int lk = tid & 31, lr = tid >> 5;
  float ar[2][2] = {{0.f,0.f},{0.f,0.f}}, ai[2][2] = {{0.f,0.f},{0.f,0.f}};
  for (int k0 = 0; k0 < DD; k0 += 32) {
    #pragma unroll
    for (int i = 0; i < 4; i++) {
      int rr = lr + i*8;
      sX[lk][rr] = IN[(size_t)(m0+rr)*DD + k0+lk];
      int o = o0 + rr;
      sW[lk][rr] = make_float2(Wr[(size_t)o*DD + k0+lk], Wi[(size_t)o*DD + k0+lk]);
    }
    __syncthreads();
    #pragma unroll
    for (int kk = 0; kk < 32; kk++) {
      float2 x0 = sX[kk][threadIdx.y], x1 = sX[kk][threadIdx.y+16];
      float2 w0 = sW[kk][threadIdx.x], w1 = sW[kk][threadIdx.x+16];
      ar[0][0] += x0.x*w0.x - x0.y*w0.y;  ai[0][0] += x0.x*w0.y + x0.y*w0.x;
      ar[0][1] += x0.x*w1.x - x0.y*w1.y;  ai[0][1] += x0.x*w1.y + x0.y*w1.x;
      ar[1][0] += x1.x*w0.x - x1.y*w0.y;  ai[1][0] += x1.x*w0.y + x1.y*w0.x;
      ar[1][1] += x1.x*w1.x - x1.y*w1.y;  ai[1][1] += x1.x*w1.y + x1.y*w1.x;
    }
    __syncthreads();
  }
  #pragma unroll
  for (int i = 0; i < 2; i++)
    #pragma unroll
    for (int j = 0; j < 2; j++) {
      int m = m0 + threadIdx.y + i*16, o = o0 + threadIdx.x + j*16;
      float brv = br[o], biv = bi[o];
      float re = ar[i][j] + brv - biv;
      float im = ai[i][j] + brv + biv;
      if (do_relu) { re = fmaxf(re, 0.f); im = fmaxf(im, 0.f); }
      OUT[(size_t)m*DD + o] = make_float2(re, im);
    }
}

// ---------- reweight = cls_label @ lbl_emb ----------
__global__ void rw_kernel(const float* __restrict__ cls, const float* __restrict__ lbl,
                          float* __restrict__ RW)
{
  int b = blockIdx.x; int d = threadIdx.x;
  float s = 0.f;
  #pragma unroll
  for (int k = 0; k < 16; k++) s += cls[b*16+k] * lbl[k*DD+d];
  RW[b*DD+d] = s;
}

// ---------- gsq[b,d,n] = |G[b,n,d]|^2 * rw[b,d] ----------
__global__ __launch_bounds__(256) void gsq_kernel(
    const float2* __restrict__ G, const float* __restrict__ RW, float* __restrict__ OUT)
{
  size_t idx = (size_t)blockIdx.x*256 + threadIdx.x;
  int d = (int)(idx & (DD-1));
  size_t bn = idx >> 8;
  int n = (int)(bn & (NPTS-1));
  int b = (int)(bn >> 11);
  float2 g = G[idx];
  OUT[((size_t)b*DD + d)*NPTS + n] = (g.x*g.x + g.y*g.y) * RW[b*DD+d];
}

// ---------- generic fused channel GEMM: Y = [res +] act(bn(W@x + bias)) ----------
// flags: 1=bias, 2=bn, 4=relu, 8=residual-add
__global__ __launch_bounds__(256) void gemm_bn_kernel(
    const float* __restrict__ W, const float* __restrict__ X, float* __restrict__ Y,
    const float* __restrict__ RES,
    const float* __restrict__ bias, const float* __restrict__ bng, const float* __restrict__ bnb,
    int O, int Cin, size_t xbs, size_t ybs, size_t rbs, int flags)
{
  int b = blockIdx.z;
  int o0 = blockIdx.y*32, n0 = blockIdx.x*32;
  const float* x = X + (size_t)b*xbs;
  __shared__ float sW[32][33], sX[32][33];
  int tid = threadIdx.y*16 + threadIdx.x;
  int lx = tid & 31, lr = tid >> 5;
  float acc[2][2] = {{0.f,0.f},{0.f,0.f}};
  for (int k0 = 0; k0 < Cin; k0 += 32) {
    #pragma unroll
    for (int i = 0; i < 4; i++) {
      int rr = lr + i*8;
      int o = o0 + rr;
      sW[lx][rr] = (o < O) ? W[(size_t)o*Cin + k0+lx] : 0.f;
      sX[rr][lx] = x[(size_t)(k0+rr)*NPTS + n0+lx];
    }
    __syncthreads();
    #pragma unroll
    for (int kk = 0; kk < 32; kk++) {
      float w0 = sW[kk][threadIdx.y], w1 = sW[kk][threadIdx.y+16];
      float x0v = sX[kk][threadIdx.x], x1v = sX[kk][threadIdx.x+16];
      acc[0][0] += w0*x0v; acc[0][1] += w0*x1v;
      acc[1][0] += w1*x0v; acc[1][1] += w1*x1v;
    }
    __syncthreads();
  }
  #pragma unroll
  for (int i = 0; i < 2; i++) {
    int o = o0 + threadIdx.y + i*16;
    if (o >= O) continue;
    float bi_ = (flags & 1) ? bias[o] : 0.f;
    float bsc = 1.f, bsh = 0.f;
    if (flags & 2) { bsc = bng[o] * rsqrtf(1.f + 1e-5f); bsh = bnb[o]; }
    #pragma unroll
    for (int j = 0; j < 2; j++) {
      int n = n0 + threadIdx.x + j*16;
      float v = acc[i][j] + bi_;
      if (flags & 2) v = v*bsc + bsh;
      if (flags & 4) v = fmaxf(v, 0.f);
      if (flags & 8) v += RES[(size_t)b*rbs + (size_t)o*NPTS + n];
      Y[(size_t)b*ybs + (size_t)o*NPTS + n] = v;
    }
  }
}

// ---------- energy[b,n,m] = sum_q xq[b,q,n]*xq[b,q,m]  (K=32) ----------
__global__ __launch_bounds__(256) void energy_kernel(const float* __restrict__ XQ,
                                                     float* __restrict__ E)
{
  int b = blockIdx.z;
  int n0 = blockIdx.y*32, m0 = blockIdx.x*32;
  const float* xq = XQ + (size_t)b*32*NPTS;
  __shared__ float sA[32][33], sB[32][33];
  int tid = threadIdx.y*16 + threadIdx.x;
  int lx = tid & 31, lq = tid >> 5;
  #pragma unroll
  for (int i = 0; i < 4; i++) {
    int q = lq + i*8;
    sA[q][lx] = xq[(size_t)q*NPTS + n0+lx];
    sB[q][lx] = xq[(size_t)q*NPTS + m0+lx];
  }
  __syncthreads();
  float acc[2][2] = {{0.f,0.f},{0.f,0.f}};
  #pragma unroll
  for (int q = 0; q < 32; q++) {
    float a0 = sA[q][threadIdx.y], a1 = sA[q][threadIdx.y+16];
    float b0 = sB[q][threadIdx.x], b1 = sB[q][threadIdx.x+16];
    acc[0][0] += a0*b0; acc[0][1] += a0*b1;
    acc[1][0] += a1*b0; acc[1][1] += a1*b1;
  }
  #pragma unroll
  for (int i = 0; i < 2; i++)
    #pragma unroll
    for (int j = 0; j < 2; j++) {
      int n = n0 + threadIdx.y + i*16, m = m0 + threadIdx.x + j*16;
      E[((size_t)b*NPTS + n)*NPTS + m] = acc[i][j];
    }
}

// ---------- row softmax (in place) ----------
__global__ __launch_bounds__(256) void softmax_kernel(float* __restrict__ E)
{
  size_t row = blockIdx.x;
  float* p = E + row*NPTS;
  int tid = threadIdx.x;
  __shared__ float red[256];
  float m = -3.4e38f;
  for (int i = tid; i < NPTS; i += 256) m = fmaxf(m, p[i]);
  red[tid] = m; __syncthreads();
  for (int w = 128; w > 0; w >>= 1) { if (tid < w) red[tid] = fmaxf(red[tid], red[tid+w]); __syncthreads(); }
  m = red[0]; __syncthreads();
  float s = 0.f;
  for (int i = tid; i < NPTS; i += 256) { float v = expf(p[i]-m); p[i] = v; s += v; }
  red[tid] = s; __syncthreads();
  for (int w = 128; w > 0; w >>= 1) { if (tid < w) red[tid] += red[tid+w]; __syncthreads(); }
  float inv = 1.f/red[0];
  for (int i = tid; i < NPTS; i += 256) p[i] *= inv;
}

// ---------- column sums of attn ----------
__global__ __launch_bounds__(256) void colsum_kernel(const float* __restrict__ E,
                                                     float* __restrict__ CS)
{
  int b = blockIdx.y;
  int m = blockIdx.x*256 + threadIdx.x;
  const float* p = E + (size_t)b*NPTS*NPTS + m;
  float s = 0.f;
  for (int n = 0; n < NPTS; n++) s += p[(size_t)n*NPTS];
  CS[b*NPTS + m] = s;
}

// ---------- xr[b,c,m] = xres[b,c,m] - sum_n xv[b,c,n]*attn[b,n,m]/(1e-9+colsum[b,m]) ----------
__global__ __launch_bounds__(256) void apply_kernel(
    const float* __restrict__ XV, const float* __restrict__ E, const float* __restrict__ CS,
    const float* __restrict__ XRES, size_t res_bs, float* __restrict__ OUT)
{
  int b = blockIdx.z;
  int c0 = blockIdx.y*32, m0 = blockIdx.x*32;
  const float* xv = XV + (size_t)b*CCH*NPTS;
  const float* e  = E + (size_t)b*NPTS*NPTS;
  __shared__ float sA[32][33], sB[32][33];
  __shared__ float sc[32];
  int tid = threadIdx.y*16 + threadIdx.x;
  if (tid < 32) sc[tid] = 1.f/(1e-9f + CS[b*NPTS + m0 + tid]);
  int lx = tid & 31, lr = tid >> 5;
  float acc[2][2] = {{0.f,0.f},{0.f,0.f}};
  for (int k0 = 0; k0 < NPTS; k0 += 32) {
    #pragma unroll
    for (int i = 0; i < 4; i++) {
      int rr = lr + i*8;
      sA[rr][lx] = xv[(size_t)(c0+rr)*NPTS + k0+lx];   // sA[cc][kk]
      sB[rr][lx] = e[(size_t)(k0+rr)*NPTS + m0+lx];    // sB[kk][mm]
    }
    __syncthreads();
    #pragma unroll
    for (int kk = 0; kk < 32; kk++) {
      float a0 = sA[threadIdx.y][kk], a1 = sA[threadIdx.y+16][kk];
      float b0 = sB[kk][threadIdx.x], b1 = sB[kk][threadIdx.x+16];
      acc[0][0] += a0*b0; acc[0][1] += a0*b1;
      acc[1][0] += a1*b0; acc[1][1] += a1*b1;
    }
    __syncthreads();
  }
  #pragma unroll
  for (int i = 0; i < 2; i++)
    #pragma unroll
    for (int j = 0; j < 2; j++) {
      int c = c0 + threadIdx.y + i*16, m = m0 + threadIdx.x + j*16;
      float v = XRES[(size_t)b*res_bs + (size_t)c*NPTS + m] - acc[i][j]*sc[threadIdx.x + j*16];
      OUT[((size_t)b*CCH + c)*NPTS + m] = v;
    }
}

// ---------- log_softmax over 50 classes + transpose to (B,N,50) ----------
__global__ __launch_bounds__(256) void lsm_kernel(const float* __restrict__ Y,
                                                  float* __restrict__ OUT)
{
  int idx = blockIdx.x*256 + threadIdx.x;   // b*NPTS + n
  int b = idx >> 11, n = idx & (NPTS-1);
  const float* p = Y + (size_t)b*NCLASS*NPTS + n;
  float m = -3.4e38f;
  #pragma unroll
  for (int k = 0; k < NCLASS; k++) m = fmaxf(m, p[(size_t)k*NPTS]);
  float s = 0.f;
  #pragma unroll
  for (int k = 0; k < NCLASS; k++) s += expf(p[(size_t)k*NPTS] - m);
  float L = m + logf(s);
  float* o = OUT + (size_t)idx*NCLASS;
  #pragma unroll
  for (int k = 0; k < NCLASS; k++) o[k] = p[(size_t)k*NPTS] - L;
}

extern "C" void kernel_launch(void* const* d_in, const int* in_sizes, int n_in,
                              void* d_out, int out_size, void* d_ws, size_t ws_size,
                              hipStream_t stream)
{
  (void)in_sizes; (void)n_in; (void)out_size; (void)ws_size;
  const float* xyz  = (const float*)d_in[0];
  const float* cls  = (const float*)d_in[1];
  const float* Amat = (const float*)d_in[2];
  const float* Bm   = (const float*)d_in[3];
  const float* W1r  = (const float*)d_in[4];
  const float* b1r  = (const float*)d_in[5];
  const float* W1i  = (const float*)d_in[6];
  const float* b1i  = (const float*)d_in[7];
  const float* W2r  = (const float*)d_in[8];
  const float* b2r  = (const float*)d_in[9];
  const float* W2i  = (const float*)d_in[10];
  const float* b2i  = (const float*)d_in[11];
  const float* lbl  = (const float*)d_in[12];
  const float* ftw1 = (const float*)d_in[13];
  const float* ftg1 = (const float*)d_in[14];
  const float* ftb1 = (const float*)d_in[15];
  const float* ftw2 = (const float*)d_in[16];
  const float* ftg2 = (const float*)d_in[17];
  const float* ftb2 = (const float*)d_in[18];
  const float* saqk = (const float*)d_in[19];
  const float* savw = (const float*)d_in[20];
  const float* savb = (const float*)d_in[21];
  const float* satw = (const float*)d_in[22];
  const float* satb = (const float*)d_in[23];
  const float* sag  = (const float*)d_in[24];
  const float* sab  = (const float*)d_in[25];
  const float* fusew= (const float*)d_in[26];
  const float* fuseg= (const float*)d_in[27];
  const float* fuseb= (const float*)d_in[28];
  const float* c1w  = (const float*)d_in[29];
  const float* c1b  = (const float*)d_in[30];
  const float* bn1g = (const float*)d_in[31];
  const float* bn1b = (const float*)d_in[32];
  const float* c2w  = (const float*)d_in[33];
  const float* c2b  = (const float*)d_in[34];
  float* out = (float*)d_out;

  // workspace layout (floats). attn (B*N*N) aliases cA+cB exactly (both dead before attn use).
  // xqt/cs/ybuf live inside gsq's region (gsq dead after ft1).
  float* ws = (float*)d_ws;
  size_t p = 0;
  float* attn = ws;                    p += (size_t)BB*NPTS*NPTS;       // 33.55M f
  float2* cA = (float2*)attn;                                           // 4.19M float2
  float2* cB = cA + (size_t)BB*NPTS*DD;                                 // 4.19M float2
  float* inn_f = ws + p;               p += (size_t)BB*DD*DD*2;
  float2* inn = (float2*)inn_f;
  float* gsq = ws + p;                 p += (size_t)BB*DD*NPTS;
  float* xqt  = gsq;                                                    // 0.52M
  float* cs   = gsq + (size_t)BB*32*NPTS;                               // 16K
  float* ybuf = cs + (size_t)BB*NPTS;                                   // 0.82M (total 1.36M < 4.19M)
  float* xfeat = ws + p;               p += (size_t)BB*CCH*NPTS;
  float* feats = ws + p;               p += (size_t)BB*4*CCH*NPTS;
  float* xt1 = ws + p;                 p += (size_t)BB*CCH*NPTS;
  float* xt2 = ws + p;                 p += (size_t)BB*CCH*NPTS;
  float* rwb = ws + p;                 p += (size_t)BB*DD;

  dim3 T2(16,16);

  ek_kernel<<<(BB*NPTS*DD)/256, 256, 0, stream>>>(xyz, Amat, Bm, cA, cB);
  inner_kernel<<<dim3(DD/32, DD/32, BB), T2, 0, stream>>>(cB, cA, inn);
  g_kernel<<<dim3(DD/32, NPTS/32, BB), T2, 0, stream>>>(cB, inn, cA);
  gnorm_kernel<<<BB*NPTS, 256, 0, stream>>>(cA);
  clinear_kernel<<<dim3(DD/32, (BB*NPTS)/32), T2, 0, stream>>>(cA, W1r, W1i, b1r, b1i, cB, 1);
  clinear_kernel<<<dim3(DD/32, (BB*NPTS)/32), T2, 0, stream>>>(cB, W2r, W2i, b2r, b2i, cA, 0);
  rw_kernel<<<BB, DD, 0, stream>>>(cls, lbl, rwb);
  gsq_kernel<<<(BB*NPTS*DD)/256, 256, 0, stream>>>(cA, rwb, gsq);

  // ft1: relu(bn(ft_w1 @ gsq))  (gsq becomes dead after this)
  gemm_bn_kernel<<<dim3(NPTS/32, CCH/32, BB), T2, 0, stream>>>(
      ftw1, gsq, xt1, nullptr, nullptr, ftg1, ftb1, CCH, DD,
      (size_t)DD*NPTS, (size_t)CCH*NPTS, 0, 2|4);
  // ft2: bn(ft_w2 @ x)
  gemm_bn_kernel<<<dim3(NPTS/32, CCH/32, BB), T2, 0, stream>>>(
      ftw2, xt1, xfeat, nullptr, nullptr, ftg2, ftb2, CCH, CCH,
      (size_t)CCH*NPTS, (size_t)CCH*NPTS, 0, 2);

  const float* xsrc = xfeat;
  size_t xbs = (size_t)CCH*NPTS;
  for (int i = 0; i < 4; i++) {
    // q/k projection (shared weights) -> (B,32,N)
    gemm_bn_kernel<<<dim3(NPTS/32, 1, BB), T2, 0, stream>>>(
        saqk + (size_t)i*32*CCH, xsrc, xqt, nullptr, nullptr, nullptr, nullptr,
        32, CCH, xbs, (size_t)32*NPTS, 0, 0);
    energy_kernel<<<dim3(NPTS/32, NPTS/32, BB), T2, 0, stream>>>(xqt, attn);
    softmax_kernel<<<BB*NPTS, 256, 0, stream>>>(attn);
    colsum_kernel<<<dim3(NPTS/256, BB), 256, 0, stream>>>(attn, cs);
    // xv = vW @ x + vb
    gemm_bn_kernel<<<dim3(NPTS/32, CCH/32, BB), T2, 0, stream>>>(
        savw + (size_t)i*CCH*CCH, xsrc, xt1, nullptr, savb + i*CCH, nullptr, nullptr,
        CCH, CCH, xbs, (size_t)CCH*NPTS, 0, 1);
    // xr = x - xv @ attn_norm
    apply_kernel<<<dim3(NPTS/32, CCH/32, BB), T2, 0, stream>>>(xt1, attn, cs, xsrc, xbs, xt2);
    // out_i = x + relu(bn(tW @ xr + tb)) -> feats slab i
    gemm_bn_kernel<<<dim3(NPTS/32, CCH/32, BB), T2, 0, stream>>>(
        satw + (size_t)i*CCH*CCH, xt2, feats + (size_t)i*CCH*NPTS, xsrc,
        satb + i*CCH, sag + i*CCH, sab + i*CCH,
        CCH, CCH, (size_t)CCH*NPTS, (size_t)4*CCH*NPTS, xbs, 1|2|4|8);
    xsrc = feats + (size_t)i*CCH*NPTS;
    xbs = (size_t)4*CCH*NPTS;
  }

  // fuse: relu(bn(fuse_w @ feats)), Cin=512
  gemm_bn_kernel<<<dim3(NPTS/32, CCH/32, BB), T2, 0, stream>>>(
      fusew, feats, xt1, nullptr, nullptr, fuseg, fuseb, CCH, 4*CCH,
      (size_t)4*CCH*NPTS, (size_t)CCH*NPTS, 0, 2|4);
  // c1: relu(bn(c1_w @ x + c1_b))
  gemm_bn_kernel<<<dim3(NPTS/32, CCH/32, BB), T2, 0, stream>>>(
      c1w, xt1, xt2, nullptr, c1b, bn1g, bn1b, CCH, CCH,
      (size_t)CCH*NPTS, (size_t)CCH*NPTS, 0, 1|2|4);
  // c2: c2_w @ x + c2_b  (O=50)
  gemm_bn_kernel<<<dim3(NPTS/32, 2, BB), T2, 0, stream>>>(
      c2w, xt2, ybuf, nullptr, c2b, nullptr, nullptr, NCLASS, CCH,
      (size_t)CCH*NPTS, (size_t)NCLASS*NPTS, 0, 1);
  lsm_kernel<<<(BB*NPTS)/256, 256, 0, stream>>>(ybuf, out);
}

// Round 3
// 2755.511 us; speedup vs baseline: 1.2394x; 1.2394x over previous
//
#include <hip/hip_runtime.h>

#define BB 8
#define NPTS 2048
#define DD 256
#define CCH 128
#define NCLASS 50

typedef __attribute__((ext_vector_type(8))) short short8;
typedef __attribute__((ext_vector_type(4))) float f32x4;
#define MFMA16(a,b,c) __builtin_amdgcn_mfma_f32_16x16x32_bf16(a,b,c,0,0,0)

__device__ __forceinline__ unsigned short f2bf(float x){
  union { float f; unsigned int u; } v; v.f = x;
  unsigned int r = v.u + 0x7FFFu + ((v.u >> 16) & 1u);
  return (unsigned short)(r >> 16);
}

// ---------- eA / eB: exp(i * pts@A), exp(i * pts@B) ----------
__global__ __launch_bounds__(256) void ek_kernel(
    const float* __restrict__ xyz, const float* __restrict__ A,
    const float* __restrict__ Bm, float2* __restrict__ EA, float2* __restrict__ EB)
{
  size_t idx = (size_t)blockIdx.x*256 + threadIdx.x;
  int d = (int)(idx & (DD-1));
  size_t bn = idx >> 8;
  int n = (int)(bn & (NPTS-1));
  int b = (int)(bn >> 11);
  float p0 = xyz[((size_t)b*3+0)*NPTS+n];
  float p1 = xyz[((size_t)b*3+1)*NPTS+n];
  float p2 = xyz[((size_t)b*3+2)*NPTS+n];
  float phA = p0*A[d] + p1*A[DD+d] + p2*A[2*DD+d];
  float phB = p0*Bm[d] + p1*Bm[DD+d] + p2*Bm[2*DD+d];
  float s, c;
  sincosf(phA, &s, &c); EA[idx] = make_float2(c, s);
  sincosf(phB, &s, &c); EB[idx] = make_float2(c, s);
}

// ---------- inner partial: part[ch][b][d][e] = sum_{n in chunk} conj(eB[n,d])*eA[n,e] ----------
__global__ __launch_bounds__(256) void inner_kernel(
    const float2* __restrict__ EB, const float2* __restrict__ EA, float2* __restrict__ PART)
{
  int z = blockIdx.z; int b = z & 7; int ch = z >> 3;
  int d0 = blockIdx.y*64, e0 = blockIdx.x*64;
  const float2* eb = EB + (size_t)b*NPTS*DD;
  const float2* ea = EA + (size_t)b*NPTS*DD;
  __shared__ float2 sB[32][65], sA[32][65];
  int tx = threadIdx.x, ty = threadIdx.y;
  int tid = ty*16 + tx;
  float ar[4][4] = {}, ai[4][4] = {};
  int nbeg = ch*512, nend = nbeg + 512;
  for (int n0 = nbeg; n0 < nend; n0 += 32) {
    #pragma unroll
    for (int i = 0; i < 8; i++) {
      int e = tid + i*256; int dd = e & 63, kk = e >> 6;
      float2 v = eb[(size_t)(n0+kk)*DD + d0+dd];
      sB[kk][dd] = make_float2(v.x, -v.y);        // conj
      sA[kk][dd] = ea[(size_t)(n0+kk)*DD + e0+dd];
    }
    __syncthreads();
    #pragma unroll
    for (int kk = 0; kk < 32; kk++) {
      float2 bb[4], aa[4];
      #pragma unroll
      for (int r = 0; r < 4; r++) bb[r] = sB[kk][ty + r*16];
      #pragma unroll
      for (int c = 0; c < 4; c++) aa[c] = sA[kk][tx + c*16];
      #pragma unroll
      for (int r = 0; r < 4; r++)
        #pragma unroll
        for (int c = 0; c < 4; c++) {
          ar[r][c] += bb[r].x*aa[c].x - bb[r].y*aa[c].y;
          ai[r][c] += bb[r].x*aa[c].y + bb[r].y*aa[c].x;
        }
    }
    __syncthreads();
  }
  float2* outp = PART + ((size_t)ch*BB + b)*DD*DD;
  #pragma unroll
  for (int r = 0; r < 4; r++)
    #pragma unroll
    for (int c = 0; c < 4; c++)
      outp[(size_t)(d0+ty+r*16)*DD + e0+tx+c*16] = make_float2(ar[r][c], ai[r][c]);
}

// ---------- reduce 4 partials ----------
__global__ __launch_bounds__(256) void innred_kernel(const float2* __restrict__ P,
                                                     float2* __restrict__ OUT)
{
  size_t i = (size_t)blockIdx.x*256 + threadIdx.x;
  const size_t S = (size_t)BB*DD*DD;
  float2 a = P[i], b = P[i+S], c = P[i+2*S], d = P[i+3*S];
  OUT[i] = make_float2(a.x+b.x+c.x+d.x, a.y+b.y+c.y+d.y);
}

// ---------- G[b,n,e] = sum_d eB[b,n,d] * inner[b,d,e] ----------
__global__ __launch_bounds__(256) void g_kernel(
    const float2* __restrict__ EB, const float2* __restrict__ INN, float2* __restrict__ G)
{
  int b = blockIdx.z;
  int n0 = blockIdx.y*64, e0 = blockIdx.x*64;
  const float2* eb = EB + (size_t)b*NPTS*DD;
  const float2* inn = INN + (size_t)b*DD*DD;
  __shared__ float2 sE[32][65], sI[32][65];   // sE[kk=d][nn], sI[kk=d][ee]
  int tx = threadIdx.x, ty = threadIdx.y;
  int tid = ty*16 + tx;
  float gr[4][4] = {}, gi[4][4] = {};
  for (int d0 = 0; d0 < DD; d0 += 32) {
    #pragma unroll
    for (int i = 0; i < 8; i++) {
      int e = tid + i*256;
      { int kk = e & 31, nn = e >> 5;           // k-contiguous read
        sE[kk][nn] = eb[(size_t)(n0+nn)*DD + d0+kk]; }
      { int ee = e & 63, kk = e >> 6;           // coalesced read
        sI[kk][ee] = inn[(size_t)(d0+kk)*DD + e0+ee]; }
    }
    __syncthreads();
    #pragma unroll
    for (int kk = 0; kk < 32; kk++) {
      float2 ee[4], ww[4];
      #pragma unroll
      for (int r = 0; r < 4; r++) ee[r] = sE[kk][ty + r*16];
      #pragma unroll
      for (int c = 0; c < 4; c++) ww[c] = sI[kk][tx + c*16];
      #pragma unroll
      for (int r = 0; r < 4; r++)
        #pragma unroll
        for (int c = 0; c < 4; c++) {
          gr[r][c] += ee[r].x*ww[c].x - ee[r].y*ww[c].y;
          gi[r][c] += ee[r].x*ww[c].y + ee[r].y*ww[c].x;
        }
    }
    __syncthreads();
  }
  #pragma unroll
  for (int r = 0; r < 4; r++)
    #pragma unroll
    for (int c = 0; c < 4; c++)
      G[((size_t)b*NPTS + n0+ty+r*16)*DD + e0+tx+c*16] = make_float2(gr[r][c], gi[r][c]);
}

// ---------- normalize each row of G to norm sqrt(D) ----------
__global__ __launch_bounds__(256) void gnorm_kernel(float2* __restrict__ G)
{
  size_t row = blockIdx.x;
  float2* p = G + row*DD;
  int tid = threadIdx.x;
  float2 v = p[tid];
  __shared__ float red[256];
  red[tid] = v.x*v.x + v.y*v.y;
  __syncthreads();
  for (int w = 128; w > 0; w >>= 1) { if (tid < w) red[tid] += red[tid+w]; __syncthreads(); }
  float sc = 16.f * rsqrtf(red[0]);
  p[tid] = make_float2(v.x*sc, v.y*sc);
}

// ---------- complex linear ----------
__global__ __launch_bounds__(256) void clinear_kernel(
    const float2* __restrict__ IN, const float* __restrict__ Wr, const float* __restrict__ Wi,
    const float* __restrict__ br, const float* __restrict__ bi,
    float2* __restrict__ OUT, int do_relu)
{
  int m0 = blockIdx.y*64, o0 = blockIdx.x*64;
  __shared__ float2 sX[32][65], sW[32][65];   // [kk][mm] / [kk][oo]
  int tx = threadIdx.x, ty = threadIdx.y;
  int tid = ty*16 + tx;
  float ar[4][4] = {}, ai[4][4] = {};
  for (int k0 = 0; k0 < DD; k0 += 32) {
    #pragma unroll
    for (int i = 0; i < 8; i++) {
      int e = tid + i*256;
      int kk = e & 31, rr = e >> 5;            // k-contiguous
      sX[kk][rr] = IN[(size_t)(m0+rr)*DD + k0+kk];
      sW[kk][rr] = make_float2(Wr[(size_t)(o0+rr)*DD + k0+kk], Wi[(size_t)(o0+rr)*DD + k0+kk]);
    }
    __syncthreads();
    #pragma unroll
    for (int kk = 0; kk < 32; kk++) {
      float2 xx[4], ww[4];
      #pragma unroll
      for (int r = 0; r < 4; r++) xx[r] = sX[kk][ty + r*16];
      #pragma unroll
      for (int c = 0; c < 4; c++) ww[c] = sW[kk][tx + c*16];
      #pragma unroll
      for (int r = 0; r < 4; r++)
        #pragma unroll
        for (int c = 0; c < 4; c++) {
          ar[r][c] += xx[r].x*ww[c].x - xx[r].y*ww[c].y;
          ai[r][c] += xx[r].x*ww[c].y + xx[r].y*ww[c].x;
        }
    }
    __syncthreads();
  }
  #pragma unroll
  for (int r = 0; r < 4; r++)
    #pragma unroll
    for (int c = 0; c < 4; c++) {
      int m = m0 + ty + r*16, o = o0 + tx + c*16;
      float brv = br[o], biv = bi[o];
      float re = ar[r][c] + brv - biv;
      float im = ai[r][c] + brv + biv;
      if (do_relu) { re = fmaxf(re, 0.f); im = fmaxf(im, 0.f); }
      OUT[(size_t)m*DD + o] = make_float2(re, im);
    }
}

// ---------- reweight ----------
__global__ void rw_kernel(const float* __restrict__ cls, const float* __restrict__ lbl,
                          float* __restrict__ RW)
{
  int b = blockIdx.x; int d = threadIdx.x;
  float s = 0.f;
  #pragma unroll
  for (int k = 0; k < 16; k++) s += cls[b*16+k] * lbl[k*DD+d];
  RW[b*DD+d] = s;
}

// ---------- gsq[b,d,n] = |G[b,n,d]|^2 * rw[b,d] ----------
__global__ __launch_bounds__(256) void gsq_kernel(
    const float2* __restrict__ G, const float* __restrict__ RW, float* __restrict__ OUT)
{
  size_t idx = (size_t)blockIdx.x*256 + threadIdx.x;
  int d = (int)(idx & (DD-1));
  size_t bn = idx >> 8;
  int n = (int)(bn & (NPTS-1));
  int b = (int)(bn >> 11);
  float2 g = G[idx];
  OUT[((size_t)b*DD + d)*NPTS + n] = (g.x*g.x + g.y*g.y) * RW[b*DD+d];
}

// ---------- generic fused channel GEMM 64x64 tile, 4x4 micro ----------
// flags: 1=bias, 2=bn, 4=relu, 8=residual-add ; ybmode: 0=fp32 Y, 1=bf16 YB [o][n]
__global__ __launch_bounds__(256) void gemm_bn_kernel(
    const float* __restrict__ W, const float* __restrict__ X, float* __restrict__ Y,
    const float* __restrict__ RES,
    const float* __restrict__ bias, const float* __restrict__ bng, const float* __restrict__ bnb,
    unsigned short* __restrict__ YB, int ybmode,
    int O, int Cin, size_t xbs, size_t ybs, size_t rbs, int flags)
{
  int b = blockIdx.z;
  int o0 = blockIdx.y*64, n0 = blockIdx.x*64;
  const float* x = X + (size_t)b*xbs;
  __shared__ float sW[32][65], sX[32][65];
  int tx = threadIdx.x, ty = threadIdx.y;
  int tid = ty*16 + tx;
  float acc[4][4] = {};
  for (int k0 = 0; k0 < Cin; k0 += 32) {
    #pragma unroll
    for (int i = 0; i < 8; i++) {
      int e = tid + i*256;
      { int kk = e & 31, oo = e >> 5;
        int o = o0 + oo;
        sW[kk][oo] = (o < O) ? W[(size_t)o*Cin + k0+kk] : 0.f; }
      { int nn = e & 63, kk = e >> 6;
        sX[kk][nn] = x[(size_t)(k0+kk)*NPTS + n0+nn]; }
    }
    __syncthreads();
    #pragma unroll
    for (int kk = 0; kk < 32; kk++) {
      float a[4], bb[4];
      #pragma unroll
      for (int r = 0; r < 4; r++) a[r] = sW[kk][ty + r*16];
      #pragma unroll
      for (int c = 0; c < 4; c++) bb[c] = sX[kk][tx + c*16];
      #pragma unroll
      for (int r = 0; r < 4; r++)
        #pragma unroll
        for (int c = 0; c < 4; c++) acc[r][c] += a[r]*bb[c];
    }
    __syncthreads();
  }
  #pragma unroll
  for (int r = 0; r < 4; r++) {
    int o = o0 + ty + r*16;
    if (o >= O) continue;
    float bi_ = (flags & 1) ? bias[o] : 0.f;
    float bsc = 1.f, bsh = 0.f;
    if (flags & 2) { bsc = bng[o] * rsqrtf(1.f + 1e-5f); bsh = bnb[o]; }
    #pragma unroll
    for (int c = 0; c < 4; c++) {
      int n = n0 + tx + c*16;
      float v = acc[r][c] + bi_;
      if (flags & 2) v = v*bsc + bsh;
      if (flags & 4) v = fmaxf(v, 0.f);
      if (flags & 8) v += RES[(size_t)b*rbs + (size_t)o*NPTS + n];
      if (ybmode == 1) YB[(size_t)b*ybs + (size_t)o*NPTS + n] = f2bf(v);
      else             Y [(size_t)b*ybs + (size_t)o*NPTS + n] = v;
    }
  }
}

// ---------- energy[b,n,m] = sum_q xq[b,q,n]*xq[b,q,m]  (K=32, fp32) ----------
__global__ __launch_bounds__(256) void energy_kernel(const float* __restrict__ XQ,
                                                     float* __restrict__ E)
{
  int b = blockIdx.z;
  int n0 = blockIdx.y*32, m0 = blockIdx.x*32;
  const float* xq = XQ + (size_t)b*32*NPTS;
  __shared__ float sA[32][33], sB[32][33];
  int tid = threadIdx.y*16 + threadIdx.x;
  int lx = tid & 31, lq = tid >> 5;
  #pragma unroll
  for (int i = 0; i < 4; i++) {
    int q = lq + i*8;
    sA[q][lx] = xq[(size_t)q*NPTS + n0+lx];
    sB[q][lx] = xq[(size_t)q*NPTS + m0+lx];
  }
  __syncthreads();
  float acc[2][2] = {};
  #pragma unroll
  for (int q = 0; q < 32; q++) {
    float a0 = sA[q][threadIdx.y], a1 = sA[q][threadIdx.y+16];
    float b0 = sB[q][threadIdx.x], b1 = sB[q][threadIdx.x+16];
    acc[0][0] += a0*b0; acc[0][1] += a0*b1;
    acc[1][0] += a1*b0; acc[1][1] += a1*b1;
  }
  #pragma unroll
  for (int i = 0; i < 2; i++)
    #pragma unroll
    for (int j = 0; j < 2; j++)
      E[((size_t)b*NPTS + n0+threadIdx.y+i*16)*NPTS + m0+threadIdx.x+j*16] = acc[i][j];
}

// ---------- per-row stats of E: mx[n], rs[n]=1/sum(exp) ----------
__global__ __launch_bounds__(256) void rowstat_kernel(const float* __restrict__ E,
                                                      float* __restrict__ MX, float* __restrict__ RS)
{
  size_t row = blockIdx.x;
  const float* p = E + row*NPTS;
  int tid = threadIdx.x;
  float v[8];
  float m = -3.4e38f;
  #pragma unroll
  for (int i = 0; i < 8; i++) { v[i] = p[tid + i*256]; m = fmaxf(m, v[i]); }
  __shared__ float red[256];
  red[tid] = m; __syncthreads();
  for (int w = 128; w > 0; w >>= 1) { if (tid < w) red[tid] = fmaxf(red[tid], red[tid+w]); __syncthreads(); }
  m = red[0]; __syncthreads();
  float s = 0.f;
  #pragma unroll
  for (int i = 0; i < 8; i++) s += expf(v[i] - m);
  red[tid] = s; __syncthreads();
  for (int w = 128; w > 0; w >>= 1) { if (tid < w) red[tid] += red[tid+w]; __syncthreads(); }
  if (tid == 0) { MX[row] = m; RS[row] = 1.f/red[0]; }
}

// ---------- attnT[m][n] = exp(E[m][n]-mx[n])*rs[n]  (E symmetric), bf16 in-place,
//            csi[m] = 1/(1e-9 + sum_n attnT[m][n]) ----------
__global__ __launch_bounds__(256) void attnT_kernel(float* __restrict__ E,
                                                    const float* __restrict__ MX,
                                                    const float* __restrict__ RS,
                                                    float* __restrict__ CSI)
{
  size_t row = blockIdx.x;                 // b*NPTS + m
  size_t b = row >> 11;
  float* p = E + row*NPTS;
  const float* mx = MX + b*NPTS;
  const float* rs = RS + b*NPTS;
  int tid = threadIdx.x;
  float t[8]; float s = 0.f;
  #pragma unroll
  for (int i = 0; i < 8; i++) {
    int n = tid + i*256;
    t[i] = expf(p[n] - mx[n]) * rs[n];
    s += t[i];
  }
  __syncthreads();                          // all reads of p done before overwrite
  unsigned short* q = (unsigned short*)E + row*4096;
  #pragma unroll
  for (int i = 0; i < 8; i++) q[tid + i*256] = f2bf(t[i]);
  __shared__ float red[256];
  red[tid] = s; __syncthreads();
  for (int w = 128; w > 0; w >>= 1) { if (tid < w) red[tid] += red[tid+w]; __syncthreads(); }
  if (tid == 0) CSI[row] = 1.f/(1e-9f + red[0]);
}

// ---------- apply (MFMA): out[c][m] = xres[c][m] - csi[m]*sum_n xv[c][n]*attnT[m][n] ----------
__global__ __launch_bounds__(512) void apply_mfma_kernel(
    const unsigned short* __restrict__ XV, const unsigned short* __restrict__ AT,
    const float* __restrict__ CSI, const float* __restrict__ XRES, size_t res_bs,
    float* __restrict__ OUT)
{
  int b = blockIdx.z;
  int m0 = blockIdx.x*64;
  const unsigned short* xv = XV + (size_t)b*CCH*NPTS;
  const unsigned short* at = AT + (size_t)b*NPTS*4096;
  int tid = threadIdx.x, lane = tid & 63, w = tid >> 6;
  int wc = (w >> 1)*32, wm = (w & 1)*32;
  int r16 = lane & 15, g4 = lane >> 4;
  f32x4 acc[2][2] = {};
  const unsigned short* pa0 = xv + (size_t)(wc + r16)*NPTS + g4*8;
  const unsigned short* pa1 = pa0 + (size_t)16*NPTS;
  const unsigned short* pb0 = at + (size_t)(m0 + wm + r16)*4096 + g4*8;
  const unsigned short* pb1 = pb0 + (size_t)16*4096;
  for (int k0 = 0; k0 < NPTS; k0 += 32) {
    short8 a0 = *(const short8*)(pa0 + k0);
    short8 a1 = *(const short8*)(pa1 + k0);
    short8 b0 = *(const short8*)(pb0 + k0);
    short8 b1 = *(const short8*)(pb1 + k0);
    acc[0][0] = MFMA16(a0, b0, acc[0][0]);
    acc[0][1] = MFMA16(a0, b1, acc[0][1]);
    acc[1][0] = MFMA16(a1, b0, acc[1][0]);
    acc[1][1] = MFMA16(a1, b1, acc[1][1]);
  }
  #pragma unroll
  for (int ca = 0; ca < 2; ca++)
    #pragma unroll
    for (int mb = 0; mb < 2; mb++) {
      int m = m0 + wm + mb*16 + r16;
      float ci = CSI[(size_t)b*NPTS + m];
      #pragma unroll
      for (int j = 0; j < 4; j++) {
        int c = wc + ca*16 + g4*4 + j;
        float v = XRES[(size_t)b*res_bs + (size_t)c*NPTS + m] - acc[ca][mb][j]*ci;
        OUT[((size_t)b*CCH + c)*NPTS + m] = v;
      }
    }
}

// ---------- log_softmax + transpose ----------
__global__ __launch_bounds__(256) void lsm_kernel(const float* __restrict__ Y,
                                                  float* __restrict__ OUT)
{
  int idx = blockIdx.x*256 + threadIdx.x;
  int b = idx >> 11, n = idx & (NPTS-1);
  const float* p = Y + (size_t)b*NCLASS*NPTS + n;
  float m = -3.4e38f;
  #pragma unroll
  for (int k = 0; k < NCLASS; k++) m = fmaxf(m, p[(size_t)k*NPTS]);
  float s = 0.f;
  #pragma unroll
  for (int k = 0; k < NCLASS; k++) s += expf(p[(size_t)k*NPTS] - m);
  float L = m + logf(s);
  float* o = OUT + (size_t)idx*NCLASS;
  #pragma unroll
  for (int k = 0; k < NCLASS; k++) o[k] = p[(size_t)k*NPTS] - L;
}

extern "C" void kernel_launch(void* const* d_in, const int* in_sizes, int n_in,
                              void* d_out, int out_size, void* d_ws, size_t ws_size,
                              hipStream_t stream)
{
  (void)in_sizes; (void)n_in; (void)out_size; (void)ws_size;
  const float* xyz  = (const float*)d_in[0];
  const float* cls  = (const float*)d_in[1];
  const float* Amat = (const float*)d_in[2];
  const float* Bm   = (const float*)d_in[3];
  const float* W1r  = (const float*)d_in[4];
  const float* b1r  = (const float*)d_in[5];
  const float* W1i  = (const float*)d_in[6];
  const float* b1i  = (const float*)d_in[7];
  const float* W2r  = (const float*)d_in[8];
  const float* b2r  = (const float*)d_in[9];
  const float* W2i  = (const float*)d_in[10];
  const float* b2i  = (const float*)d_in[11];
  const float* lbl  = (const float*)d_in[12];
  const float* ftw1 = (const float*)d_in[13];
  const float* ftg1 = (const float*)d_in[14];
  const float* ftb1 = (const float*)d_in[15];
  const float* ftw2 = (const float*)d_in[16];
  const float* ftg2 = (const float*)d_in[17];
  const float* ftb2 = (const float*)d_in[18];
  const float* saqk = (const float*)d_in[19];
  const float* savw = (const float*)d_in[20];
  const float* savb = (const float*)d_in[21];
  const float* satw = (const float*)d_in[22];
  const float* satb = (const float*)d_in[23];
  const float* sag  = (const float*)d_in[24];
  const float* sab  = (const float*)d_in[25];
  const float* fusew= (const float*)d_in[26];
  const float* fuseg= (const float*)d_in[27];
  const float* fuseb= (const float*)d_in[28];
  const float* c1w  = (const float*)d_in[29];
  const float* c1b  = (const float*)d_in[30];
  const float* bn1g = (const float*)d_in[31];
  const float* bn1b = (const float*)d_in[32];
  const float* c2w  = (const float*)d_in[33];
  const float* c2b  = (const float*)d_in[34];
  float* out = (float*)d_out;

  float* ws = (float*)d_ws;
  size_t p = 0;
  float* E = ws;                       p += (size_t)BB*NPTS*NPTS;       // E / attnT(bf16 in-place)
  float2* cA = (float2*)E;                                              // VecKM phase aliases
  float2* cB = cA + (size_t)BB*NPTS*DD;
  float* inn_f = ws + p;               p += (size_t)BB*DD*DD*2;
  float2* inn = (float2*)inn_f;
  float* gsq = ws + p;                 p += (size_t)BB*DD*NPTS;
  // carve SA-phase small buffers out of gsq region (gsq dead after ft1)
  float* xqt  = gsq;                                   // 8*32*2048 = 524288 f
  float* mxv  = gsq + 524288;                          // 16384 f
  float* rsv  = mxv + 16384;
  float* csi  = rsv + 16384;
  float* ybuf = csi + 16384;                           // 8*50*2048 = 819200 f
  unsigned short* xvb = (unsigned short*)(ybuf + 819200);  // 8*128*2048 ushort
  float* xfeat = ws + p;               p += (size_t)BB*CCH*NPTS;
  float* feats = ws + p;               p += (size_t)BB*4*CCH*NPTS;
  float2* inn_part = (float2*)feats;                   // VecKM phase alias (needs 4.2M f2)
  float* xt1 = ws + p;                 p += (size_t)BB*CCH*NPTS;
  float* xt2 = ws + p;                 p += (size_t)BB*CCH*NPTS;
  float* rwb = ws + p;                 p += (size_t)BB*DD;

  dim3 T2(16,16);

  ek_kernel<<<(BB*NPTS*DD)/256, 256, 0, stream>>>(xyz, Amat, Bm, cA, cB);
  inner_kernel<<<dim3(DD/64, DD/64, BB*4), T2, 0, stream>>>(cB, cA, inn_part);
  innred_kernel<<<(BB*DD*DD)/256, 256, 0, stream>>>(inn_part, inn);
  g_kernel<<<dim3(DD/64, NPTS/64, BB), T2, 0, stream>>>(cB, inn, cA);
  gnorm_kernel<<<BB*NPTS, 256, 0, stream>>>(cA);
  clinear_kernel<<<dim3(DD/64, (BB*NPTS)/64), T2, 0, stream>>>(cA, W1r, W1i, b1r, b1i, cB, 1);
  clinear_kernel<<<dim3(DD/64, (BB*NPTS)/64), T2, 0, stream>>>(cB, W2r, W2i, b2r, b2i, cA, 0);
  rw_kernel<<<BB, DD, 0, stream>>>(cls, lbl, rwb);
  gsq_kernel<<<(BB*NPTS*DD)/256, 256, 0, stream>>>(cA, rwb, gsq);

  gemm_bn_kernel<<<dim3(NPTS/64, CCH/64, BB), T2, 0, stream>>>(
      ftw1, gsq, xt1, nullptr, nullptr, ftg1, ftb1, nullptr, 0, CCH, DD,
      (size_t)DD*NPTS, (size_t)CCH*NPTS, 0, 2|4);
  gemm_bn_kernel<<<dim3(NPTS/64, CCH/64, BB), T2, 0, stream>>>(
      ftw2, xt1, xfeat, nullptr, nullptr, ftg2, ftb2, nullptr, 0, CCH, CCH,
      (size_t)CCH*NPTS, (size_t)CCH*NPTS, 0, 2);

  const float* xsrc = xfeat;
  size_t xbs = (size_t)CCH*NPTS;
  for (int i = 0; i < 4; i++) {
    // q/k projection (shared weights) -> fp32 (B,32,N)
    gemm_bn_kernel<<<dim3(NPTS/64, 1, BB), T2, 0, stream>>>(
        saqk + (size_t)i*32*CCH, xsrc, xqt, nullptr, nullptr, nullptr, nullptr,
        nullptr, 0, 32, CCH, xbs, (size_t)32*NPTS, 0, 0);
    energy_kernel<<<dim3(NPTS/32, NPTS/32, BB), T2, 0, stream>>>(xqt, E);
    rowstat_kernel<<<BB*NPTS, 256, 0, stream>>>(E, mxv, rsv);
    attnT_kernel<<<BB*NPTS, 256, 0, stream>>>(E, mxv, rsv, csi);
    // xv = vW @ x + vb  -> bf16
    gemm_bn_kernel<<<dim3(NPTS/64, CCH/64, BB), T2, 0, stream>>>(
        savw + (size_t)i*CCH*CCH, xsrc, nullptr, nullptr, savb + i*CCH, nullptr, nullptr,
        xvb, 1, CCH, CCH, xbs, (size_t)CCH*NPTS, 0, 1);
    // xr = x - (xv @ attn) * csi   (MFMA)
    apply_mfma_kernel<<<dim3(NPTS/64, 1, BB), 512, 0, stream>>>(
        xvb, (const unsigned short*)E, csi, xsrc, xbs, xt2);
    // out_i = x + relu(bn(tW @ xr + tb))
    gemm_bn_kernel<<<dim3(NPTS/64, CCH/64, BB), T2, 0, stream>>>(
        satw + (size_t)i*CCH*CCH, xt2, feats + (size_t)i*CCH*NPTS, xsrc,
        satb + i*CCH, sag + i*CCH, sab + i*CCH, nullptr, 0,
        CCH, CCH, (size_t)CCH*NPTS, (size_t)4*CCH*NPTS, xbs, 1|2|4|8);
    xsrc = feats + (size_t)i*CCH*NPTS;
    xbs = (size_t)4*CCH*NPTS;
  }

  gemm_bn_kernel<<<dim3(NPTS/64, CCH/64, BB), T2, 0, stream>>>(
      fusew, feats, xt1, nullptr, nullptr, fuseg, fuseb, nullptr, 0, CCH, 4*CCH,
      (size_t)4*CCH*NPTS, (size_t)CCH*NPTS, 0, 2|4);
  gemm_bn_kernel<<<dim3(NPTS/64, CCH/64, BB), T2, 0, stream>>>(
      c1w, xt1, xt2, nullptr, c1b, bn1g, bn1b, nullptr, 0, CCH, CCH,
      (size_t)CCH*NPTS, (size_t)CCH*NPTS, 0, 1|2|4);
  gemm_bn_kernel<<<dim3(NPTS/64, 1, BB), T2, 0, stream>>>(
      c2w, xt2, ybuf, nullptr, c2b, nullptr, nullptr, nullptr, 0, NCLASS, CCH,
      (size_t)CCH*NPTS, (size_t)NCLASS*NPTS, 0, 1);
  lsm_kernel<<<(BB*NPTS)/256, 256, 0, stream>>>(ybuf, out);
}

// Round 4
// 1254.047 us; speedup vs baseline: 2.7234x; 2.1973x over previous
//
#include <hip/hip_runtime.h>

#define BB 8
#define NPTS 2048
#define DD 256
#define CCH 128
#define NCLASS 50

typedef __attribute__((ext_vector_type(8))) short short8;
typedef __attribute__((ext_vector_type(4))) float f32x4;
typedef unsigned short u16;
#define MFMA16(a,b,c) __builtin_amdgcn_mfma_f32_16x16x32_bf16(a,b,c,0,0,0)

__device__ __forceinline__ u16 f2bf(float x){
  union { float f; unsigned int u; } v; v.f = x;
  unsigned int r = v.u + 0x7FFFu + ((v.u >> 16) & 1u);
  return (u16)(r >> 16);
}
__device__ __forceinline__ float bf2f(u16 u){
  union { unsigned int u32; float f; } v; v.u32 = ((unsigned int)u) << 16; return v.f;
}
__device__ __forceinline__ void split2(float x, u16& h, u16& l){
  h = f2bf(x); l = f2bf(x - bf2f(h));
}
__device__ __forceinline__ short8 ld8(const u16* p){ return *(const short8*)p; }
__device__ __forceinline__ short8 zero8(){ short8 z = {0,0,0,0,0,0,0,0}; return z; }
__device__ __forceinline__ void split8(const float* v, short8& H, short8& L){
  #pragma unroll
  for (int i = 0; i < 8; i++) { u16 h, l; split2(v[i], h, l); H[i] = (short)h; L[i] = (short)l; }
}

// ---------- ek1: eA^T, eB^T split bf16 [b][d][n] ----------
__global__ __launch_bounds__(256) void ek1_kernel(
    const float* __restrict__ xyz, const float* __restrict__ A, const float* __restrict__ Bm,
    u16* __restrict__ ATrh, u16* __restrict__ ATrl, u16* __restrict__ ATih, u16* __restrict__ ATil,
    u16* __restrict__ BTrh, u16* __restrict__ BTrl, u16* __restrict__ BTih, u16* __restrict__ BTil)
{
  size_t idx = (size_t)blockIdx.x*256 + threadIdx.x;
  int n = (int)(idx & (NPTS-1));
  int d = (int)((idx >> 11) & (DD-1));
  int b = (int)(idx >> 19);
  float p0 = xyz[((size_t)b*3+0)*NPTS+n];
  float p1 = xyz[((size_t)b*3+1)*NPTS+n];
  float p2 = xyz[((size_t)b*3+2)*NPTS+n];
  float phA = p0*A[d] + p1*A[DD+d] + p2*A[2*DD+d];
  float phB = p0*Bm[d] + p1*Bm[DD+d] + p2*Bm[2*DD+d];
  float sa, ca, sb, cb;
  sincosf(phA, &sa, &ca);
  sincosf(phB, &sb, &cb);
  size_t off = ((size_t)b*DD + d)*NPTS + n;
  u16 h, l;
  split2(ca, h, l); ATrh[off] = h; ATrl[off] = l;
  split2(sa, h, l); ATih[off] = h; ATil[off] = l;
  split2(cb, h, l); BTrh[off] = h; BTrl[off] = l;
  split2(sb, h, l); BTih[off] = h; BTil[off] = l;
}

// ---------- ek2: eB split bf16 [b][n][d] (recompute sincos) ----------
__global__ __launch_bounds__(256) void ek2_kernel(
    const float* __restrict__ xyz, const float* __restrict__ Bm,
    u16* __restrict__ Brh, u16* __restrict__ Brl, u16* __restrict__ Bih, u16* __restrict__ Bil)
{
  size_t idx = (size_t)blockIdx.x*256 + threadIdx.x;
  int d = (int)(idx & (DD-1));
  int n = (int)((idx >> 8) & (NPTS-1));
  int b = (int)(idx >> 19);
  float p0 = xyz[((size_t)b*3+0)*NPTS+n];
  float p1 = xyz[((size_t)b*3+1)*NPTS+n];
  float p2 = xyz[((size_t)b*3+2)*NPTS+n];
  float phB = p0*Bm[d] + p1*Bm[DD+d] + p2*Bm[2*DD+d];
  float sb, cb;
  sincosf(phB, &sb, &cb);
  size_t off = ((size_t)b*NPTS + n)*DD + d;
  u16 h, l;
  split2(cb, h, l); Brh[off] = h; Brl[off] = l;
  split2(sb, h, l); Bih[off] = h; Bil[off] = l;
}

// ---------- innT[e][d] = inner[d][e] = sum_n conj(eB[n,d])*eA[n,e]  (split MFMA) ----------
// Re = Ar.Br + Ai.Bi ; Im = Ai.Br - Ar.Bi   (A = eA^T rows e, B = eB^T rows d)
__global__ __launch_bounds__(256) void inner_mfma_kernel(
    const u16* __restrict__ ATrh, const u16* __restrict__ ATrl,
    const u16* __restrict__ ATih, const u16* __restrict__ ATil,
    const u16* __restrict__ BTrh, const u16* __restrict__ BTrl,
    const u16* __restrict__ BTih, const u16* __restrict__ BTil,
    u16* __restrict__ Irh, u16* __restrict__ Irl, u16* __restrict__ Iih, u16* __restrict__ Iil)
{
  int b = blockIdx.z;
  int e0 = blockIdx.y*64, d0 = blockIdx.x*64;
  int tid = threadIdx.x, lane = tid & 63, w = tid >> 6;
  int wr = (w >> 1)*32, wc = (w & 1)*32;
  int r16 = lane & 15, g4 = lane >> 4;
  f32x4 re[2][2] = {}, ip[2][2] = {}, iq[2][2] = {};
  size_t ar_[2], br_[2];
  #pragma unroll
  for (int rg = 0; rg < 2; rg++) {
    ar_[rg] = ((size_t)b*DD + (e0 + wr + rg*16 + r16))*NPTS + g4*8;
    br_[rg] = ((size_t)b*DD + (d0 + wc + rg*16 + r16))*NPTS + g4*8;
  }
  for (int k0 = 0; k0 < NPTS; k0 += 32) {
    short8 arh[2], arl[2], aih[2], ail[2], brh[2], brl[2], bih[2], bil[2];
    #pragma unroll
    for (int rg = 0; rg < 2; rg++) {
      arh[rg] = ld8(ATrh + ar_[rg] + k0); arl[rg] = ld8(ATrl + ar_[rg] + k0);
      aih[rg] = ld8(ATih + ar_[rg] + k0); ail[rg] = ld8(ATil + ar_[rg] + k0);
      brh[rg] = ld8(BTrh + br_[rg] + k0); brl[rg] = ld8(BTrl + br_[rg] + k0);
      bih[rg] = ld8(BTih + br_[rg] + k0); bil[rg] = ld8(BTil + br_[rg] + k0);
    }
    #pragma unroll
    for (int ra = 0; ra < 2; ra++)
      #pragma unroll
      for (int rb = 0; rb < 2; rb++) {
        re[ra][rb] = MFMA16(arh[ra], brh[rb], re[ra][rb]);
        re[ra][rb] = MFMA16(arh[ra], brl[rb], re[ra][rb]);
        re[ra][rb] = MFMA16(arl[ra], brh[rb], re[ra][rb]);
        re[ra][rb] = MFMA16(aih[ra], bih[rb], re[ra][rb]);
        re[ra][rb] = MFMA16(aih[ra], bil[rb], re[ra][rb]);
        re[ra][rb] = MFMA16(ail[ra], bih[rb], re[ra][rb]);
        ip[ra][rb] = MFMA16(aih[ra], brh[rb], ip[ra][rb]);
        ip[ra][rb] = MFMA16(aih[ra], brl[rb], ip[ra][rb]);
        ip[ra][rb] = MFMA16(ail[ra], brh[rb], ip[ra][rb]);
        iq[ra][rb] = MFMA16(arh[ra], bih[rb], iq[ra][rb]);
        iq[ra][rb] = MFMA16(arh[ra], bil[rb], iq[ra][rb]);
        iq[ra][rb] = MFMA16(arl[ra], bih[rb], iq[ra][rb]);
      }
  }
  #pragma unroll
  for (int ra = 0; ra < 2; ra++)
    #pragma unroll
    for (int rb = 0; rb < 2; rb++)
      #pragma unroll
      for (int j = 0; j < 4; j++) {
        int e = e0 + wr + ra*16 + g4*4 + j;
        int d = d0 + wc + rb*16 + r16;
        size_t off = ((size_t)b*DD + e)*DD + d;
        u16 h, l;
        split2(re[ra][rb][j], h, l); Irh[off] = h; Irl[off] = l;
        split2(ip[ra][rb][j] - iq[ra][rb][j], h, l); Iih[off] = h; Iil[off] = l;
      }
}

// ---------- G[n][e] = sum_d eB[n,d]*inner[d,e]  (A=eBn rows n, B=innT rows e) ----------
// Re = Ar.Br - Ai.Bi ; Im = Ar.Bi + Ai.Br
__global__ __launch_bounds__(256) void g_mfma_kernel(
    const u16* __restrict__ Brh, const u16* __restrict__ Brl,
    const u16* __restrict__ Bih, const u16* __restrict__ Bil,
    const u16* __restrict__ Irh, const u16* __restrict__ Irl,
    const u16* __restrict__ Iih, const u16* __restrict__ Iil,
    float2* __restrict__ G)
{
  int b = blockIdx.z;
  int n0 = blockIdx.y*64, e0 = blockIdx.x*64;
  int tid = threadIdx.x, lane = tid & 63, w = tid >> 6;
  int wr = (w >> 1)*32, wc = (w & 1)*32;
  int r16 = lane & 15, g4 = lane >> 4;
  f32x4 p[2][2] = {}, q[2][2] = {}, im[2][2] = {};
  size_t ar_[2], br_[2];
  #pragma unroll
  for (int rg = 0; rg < 2; rg++) {
    ar_[rg] = ((size_t)b*NPTS + (n0 + wr + rg*16 + r16))*DD + g4*8;
    br_[rg] = ((size_t)b*DD + (e0 + wc + rg*16 + r16))*DD + g4*8;
  }
  for (int k0 = 0; k0 < DD; k0 += 32) {
    short8 arh[2], arl[2], aih[2], ail[2], brh[2], brl[2], bih[2], bil[2];
    #pragma unroll
    for (int rg = 0; rg < 2; rg++) {
      arh[rg] = ld8(Brh + ar_[rg] + k0); arl[rg] = ld8(Brl + ar_[rg] + k0);
      aih[rg] = ld8(Bih + ar_[rg] + k0); ail[rg] = ld8(Bil + ar_[rg] + k0);
      brh[rg] = ld8(Irh + br_[rg] + k0); brl[rg] = ld8(Irl + br_[rg] + k0);
      bih[rg] = ld8(Iih + br_[rg] + k0); bil[rg] = ld8(Iil + br_[rg] + k0);
    }
    #pragma unroll
    for (int ra = 0; ra < 2; ra++)
      #pragma unroll
      for (int rb = 0; rb < 2; rb++) {
        p[ra][rb] = MFMA16(arh[ra], brh[rb], p[ra][rb]);
        p[ra][rb] = MFMA16(arh[ra], brl[rb], p[ra][rb]);
        p[ra][rb] = MFMA16(arl[ra], brh[rb], p[ra][rb]);
        q[ra][rb] = MFMA16(aih[ra], bih[rb], q[ra][rb]);
        q[ra][rb] = MFMA16(aih[ra], bil[rb], q[ra][rb]);
        q[ra][rb] = MFMA16(ail[ra], bih[rb], q[ra][rb]);
        im[ra][rb] = MFMA16(arh[ra], bih[rb], im[ra][rb]);
        im[ra][rb] = MFMA16(arh[ra], bil[rb], im[ra][rb]);
        im[ra][rb] = MFMA16(arl[ra], bih[rb], im[ra][rb]);
        im[ra][rb] = MFMA16(aih[ra], brh[rb], im[ra][rb]);
        im[ra][rb] = MFMA16(aih[ra], brl[rb], im[ra][rb]);
        im[ra][rb] = MFMA16(ail[ra], brh[rb], im[ra][rb]);
      }
  }
  #pragma unroll
  for (int ra = 0; ra < 2; ra++)
    #pragma unroll
    for (int rb = 0; rb < 2; rb++)
      #pragma unroll
      for (int j = 0; j < 4; j++) {
        int n = n0 + wr + ra*16 + g4*4 + j;
        int e = e0 + wc + rb*16 + r16;
        G[((size_t)b*NPTS + n)*DD + e] = make_float2(p[ra][rb][j] - q[ra][rb][j], im[ra][rb][j]);
      }
}

// ---------- normalize each row of G to norm sqrt(D) ----------
__global__ __launch_bounds__(256) void gnorm_kernel(float2* __restrict__ G)
{
  size_t row = blockIdx.x;
  float2* p = G + row*DD;
  int tid = threadIdx.x;
  float2 v = p[tid];
  __shared__ float red[256];
  red[tid] = v.x*v.x + v.y*v.y;
  __syncthreads();
  for (int w = 128; w > 0; w >>= 1) { if (tid < w) red[tid] += red[tid+w]; __syncthreads(); }
  float sc = 16.f * rsqrtf(red[0]);
  p[tid] = make_float2(v.x*sc, v.y*sc);
}

// ---------- complex linear (split MFMA): out[m][o] = x[m][:].(Wr[o]+iWi[o]) + bias ----------
__global__ __launch_bounds__(256) void clinear_mfma_kernel(
    const float2* __restrict__ IN, const float* __restrict__ Wr, const float* __restrict__ Wi,
    const float* __restrict__ br, const float* __restrict__ bi,
    float2* __restrict__ OUT, int do_relu)
{
  int m0 = blockIdx.y*64, o0 = blockIdx.x*64;
  int tid = threadIdx.x, lane = tid & 63, w = tid >> 6;
  int wr = (w >> 1)*32, wc = (w & 1)*32;
  int r16 = lane & 15, g4 = lane >> 4;
  f32x4 p[2][2] = {}, q[2][2] = {}, im[2][2] = {};
  int mrow[2], orow[2];
  #pragma unroll
  for (int rg = 0; rg < 2; rg++) {
    mrow[rg] = m0 + wr + rg*16 + r16;
    orow[rg] = o0 + wc + rg*16 + r16;
  }
  for (int k0 = 0; k0 < DD; k0 += 32) {
    short8 arh[2], arl[2], aih[2], ail[2], brh[2], brl[2], bih[2], bil[2];
    #pragma unroll
    for (int rg = 0; rg < 2; rg++) {
      const float2* pa = IN + (size_t)mrow[rg]*DD + k0 + g4*8;
      float vr[8], vi[8];
      #pragma unroll
      for (int j = 0; j < 8; j++) { float2 t = pa[j]; vr[j] = t.x; vi[j] = t.y; }
      split8(vr, arh[rg], arl[rg]); split8(vi, aih[rg], ail[rg]);
      const float* pr = Wr + (size_t)orow[rg]*DD + k0 + g4*8;
      const float* pi = Wi + (size_t)orow[rg]*DD + k0 + g4*8;
      float wv[8];
      #pragma unroll
      for (int j = 0; j < 8; j++) wv[j] = pr[j];
      split8(wv, brh[rg], brl[rg]);
      #pragma unroll
      for (int j = 0; j < 8; j++) wv[j] = pi[j];
      split8(wv, bih[rg], bil[rg]);
    }
    #pragma unroll
    for (int ra = 0; ra < 2; ra++)
      #pragma unroll
      for (int rb = 0; rb < 2; rb++) {
        p[ra][rb] = MFMA16(arh[ra], brh[rb], p[ra][rb]);
        p[ra][rb] = MFMA16(arh[ra], brl[rb], p[ra][rb]);
        p[ra][rb] = MFMA16(arl[ra], brh[rb], p[ra][rb]);
        q[ra][rb] = MFMA16(aih[ra], bih[rb], q[ra][rb]);
        q[ra][rb] = MFMA16(aih[ra], bil[rb], q[ra][rb]);
        q[ra][rb] = MFMA16(ail[ra], bih[rb], q[ra][rb]);
        im[ra][rb] = MFMA16(arh[ra], bih[rb], im[ra][rb]);
        im[ra][rb] = MFMA16(arh[ra], bil[rb], im[ra][rb]);
        im[ra][rb] = MFMA16(arl[ra], bih[rb], im[ra][rb]);
        im[ra][rb] = MFMA16(aih[ra], brh[rb], im[ra][rb]);
        im[ra][rb] = MFMA16(aih[ra], brl[rb], im[ra][rb]);
        im[ra][rb] = MFMA16(ail[ra], brh[rb], im[ra][rb]);
      }
  }
  #pragma unroll
  for (int ra = 0; ra < 2; ra++)
    #pragma unroll
    for (int rb = 0; rb < 2; rb++)
      #pragma unroll
      for (int j = 0; j < 4; j++) {
        int m = m0 + wr + ra*16 + g4*4 + j;
        int o = o0 + wc + rb*16 + r16;
        float brv = br[o], biv = bi[o];
        float re = p[ra][rb][j] - q[ra][rb][j] + brv - biv;
        float iv = im[ra][rb][j] + brv + biv;
        if (do_relu) { re = fmaxf(re, 0.f); iv = fmaxf(iv, 0.f); }
        OUT[(size_t)m*DD + o] = make_float2(re, iv);
      }
}

// ---------- reweight ----------
__global__ void rw_kernel(const float* __restrict__ cls, const float* __restrict__ lbl,
                          float* __restrict__ RW)
{
  int b = blockIdx.x; int d = threadIdx.x;
  float s = 0.f;
  #pragma unroll
  for (int k = 0; k < 16; k++) s += cls[b*16+k] * lbl[k*DD+d];
  RW[b*DD+d] = s;
}

// ---------- gsq[b,d,n] = |G[b,n,d]|^2 * rw[b,d] ----------
__global__ __launch_bounds__(256) void gsq_kernel(
    const float2* __restrict__ G, const float* __restrict__ RW, float* __restrict__ OUT)
{
  size_t idx = (size_t)blockIdx.x*256 + threadIdx.x;
  int d = (int)(idx & (DD-1));
  size_t bn = idx >> 8;
  int n = (int)(bn & (NPTS-1));
  int b = (int)(bn >> 11);
  float2 g = G[idx];
  OUT[((size_t)b*DD + d)*NPTS + n] = (g.x*g.x + g.y*g.y) * RW[b*DD+d];
}

// ---------- sgemm (split MFMA): Y[o][n] = epilogue(W[o][:] @ X[:][n]) ----------
// flags: 1=bias, 2=bn, 4=relu, 8=residual ; ybmode: 0=fp32, 1=bf16 [o][n], 2=split xqT [n][32]
__global__ __launch_bounds__(256) void sgemm_kernel(
    const float* __restrict__ W, const float* __restrict__ X, float* __restrict__ Y,
    const float* __restrict__ RES,
    const float* __restrict__ bias, const float* __restrict__ bng, const float* __restrict__ bnb,
    u16* __restrict__ YBh, u16* __restrict__ YBl, int ybmode,
    int O, int Cin, size_t xbs, size_t ybs, size_t rbs, int flags)
{
  int b = blockIdx.z;
  int n0 = blockIdx.x*64, o0 = blockIdx.y*64;
  const float* x = X + (size_t)b*xbs;
  __shared__ u16 sXh[64][40], sXl[64][40];
  int tid = threadIdx.x, lane = tid & 63, w = tid >> 6;
  int wo = (w >> 1)*32, wn = (w & 1)*32;
  int r16 = lane & 15, g4 = lane >> 4;
  f32x4 acc[2][2] = {};
  int stc = tid >> 3;          // 0..31 (k row)
  int stn = (tid & 7)*8;       // 0..56 (n octet)
  for (int k0 = 0; k0 < Cin; k0 += 32) {
    const float* px = x + (size_t)(k0+stc)*NPTS + n0 + stn;
    float4 u0 = *(const float4*)px;
    float4 u1 = *(const float4*)(px+4);
    float v[8] = {u0.x,u0.y,u0.z,u0.w,u1.x,u1.y,u1.z,u1.w};
    __syncthreads();
    #pragma unroll
    for (int j = 0; j < 8; j++) {
      u16 h, l; split2(v[j], h, l);
      sXh[stn+j][stc] = h; sXl[stn+j][stc] = l;
    }
    __syncthreads();
    short8 awh[2], awl[2], bxh[2], bxl[2];
    #pragma unroll
    for (int rg = 0; rg < 2; rg++) {
      int orow = o0 + wo + rg*16 + r16;
      if (orow < O) {
        const float* pw = W + (size_t)orow*Cin + k0 + g4*8;
        float wv[8];
        #pragma unroll
        for (int j = 0; j < 8; j++) wv[j] = pw[j];
        split8(wv, awh[rg], awl[rg]);
      } else { awh[rg] = zero8(); awl[rg] = zero8(); }
      bxh[rg] = ld8(&sXh[wn + rg*16 + r16][g4*8]);
      bxl[rg] = ld8(&sXl[wn + rg*16 + r16][g4*8]);
    }
    #pragma unroll
    for (int ra = 0; ra < 2; ra++)
      #pragma unroll
      for (int rb = 0; rb < 2; rb++) {
        acc[ra][rb] = MFMA16(awh[ra], bxh[rb], acc[ra][rb]);
        acc[ra][rb] = MFMA16(awh[ra], bxl[rb], acc[ra][rb]);
        acc[ra][rb] = MFMA16(awl[ra], bxh[rb], acc[ra][rb]);
      }
  }
  #pragma unroll
  for (int ra = 0; ra < 2; ra++)
    #pragma unroll
    for (int rb = 0; rb < 2; rb++)
      #pragma unroll
      for (int j = 0; j < 4; j++) {
        int o = o0 + wo + ra*16 + g4*4 + j;
        if (o >= O) continue;
        int n = n0 + wn + rb*16 + r16;
        float v = acc[ra][rb][j];
        if (flags & 1) v += bias[o];
        if (flags & 2) v = v * (bng[o] * rsqrtf(1.f + 1e-5f)) + bnb[o];
        if (flags & 4) v = fmaxf(v, 0.f);
        if (flags & 8) v += RES[(size_t)b*rbs + (size_t)o*NPTS + n];
        if (ybmode == 0) Y[(size_t)b*ybs + (size_t)o*NPTS + n] = v;
        else if (ybmode == 1) YBh[(size_t)b*ybs + (size_t)o*NPTS + n] = f2bf(v);
        else {
          u16 h, l; split2(v, h, l);
          size_t off = ((size_t)b*NPTS + n)*32 + o;
          YBh[off] = h; YBl[off] = l;
        }
      }
}

// ---------- energy (split MFMA, K=32): E[n][m] = sum_q xqT[n][q]*xqT[m][q] ----------
__global__ __launch_bounds__(256) void energy_mfma_kernel(
    const u16* __restrict__ Qh, const u16* __restrict__ Ql, float* __restrict__ E)
{
  int b = blockIdx.z;
  int n0 = blockIdx.y*64, m0 = blockIdx.x*64;
  size_t base = (size_t)b*NPTS*32;
  int tid = threadIdx.x, lane = tid & 63, w = tid >> 6;
  int wn = (w >> 1)*32, wm = (w & 1)*32;
  int r16 = lane & 15, g4 = lane >> 4;
  f32x4 acc[2][2] = {};
  short8 ah[2], al[2], bh[2], bl[2];
  #pragma unroll
  for (int rg = 0; rg < 2; rg++) {
    size_t ao = base + (size_t)(n0 + wn + rg*16 + r16)*32 + g4*8;
    size_t bo = base + (size_t)(m0 + wm + rg*16 + r16)*32 + g4*8;
    ah[rg] = ld8(Qh + ao); al[rg] = ld8(Ql + ao);
    bh[rg] = ld8(Qh + bo); bl[rg] = ld8(Ql + bo);
  }
  #pragma unroll
  for (int ra = 0; ra < 2; ra++)
    #pragma unroll
    for (int rb = 0; rb < 2; rb++) {
      acc[ra][rb] = MFMA16(ah[ra], bh[rb], acc[ra][rb]);
      acc[ra][rb] = MFMA16(ah[ra], bl[rb], acc[ra][rb]);
      acc[ra][rb] = MFMA16(al[ra], bh[rb], acc[ra][rb]);
    }
  #pragma unroll
  for (int ra = 0; ra < 2; ra++)
    #pragma unroll
    for (int rb = 0; rb < 2; rb++)
      #pragma unroll
      for (int j = 0; j < 4; j++) {
        int n = n0 + wn + ra*16 + g4*4 + j;
        int m = m0 + wm + rb*16 + r16;
        E[((size_t)b*NPTS + n)*NPTS + m] = acc[ra][rb][j];
      }
}

// ---------- per-row stats of E ----------
__global__ __launch_bounds__(256) void rowstat_kernel(const float* __restrict__ E,
                                                      float* __restrict__ MX, float* __restrict__ RS)
{
  size_t row = blockIdx.x;
  const float* p = E + row*NPTS;
  int tid = threadIdx.x;
  float v[8];
  float m = -3.4e38f;
  #pragma unroll
  for (int i = 0; i < 8; i++) { v[i] = p[tid + i*256]; m = fmaxf(m, v[i]); }
  __shared__ float red[256];
  red[tid] = m; __syncthreads();
  for (int w = 128; w > 0; w >>= 1) { if (tid < w) red[tid] = fmaxf(red[tid], red[tid+w]); __syncthreads(); }
  m = red[0]; __syncthreads();
  float s = 0.f;
  #pragma unroll
  for (int i = 0; i < 8; i++) s += expf(v[i] - m);
  red[tid] = s; __syncthreads();
  for (int w = 128; w > 0; w >>= 1) { if (tid < w) red[tid] += red[tid+w]; __syncthreads(); }
  if (tid == 0) { MX[row] = m; RS[row] = 1.f/red[0]; }
}

// ---------- attnT bf16 in-place + column-renorm sums ----------
__global__ __launch_bounds__(256) void attnT_kernel(float* __restrict__ E,
                                                    const float* __restrict__ MX,
                                                    const float* __restrict__ RS,
                                                    float* __restrict__ CSI)
{
  size_t row = blockIdx.x;                 // b*NPTS + m
  size_t b = row >> 11;
  float* p = E + row*NPTS;
  const float* mx = MX + b*NPTS;
  const float* rs = RS + b*NPTS;
  int tid = threadIdx.x;
  float t[8]; float s = 0.f;
  #pragma unroll
  for (int i = 0; i < 8; i++) {
    int n = tid + i*256;
    t[i] = expf(p[n] - mx[n]) * rs[n];
    s += t[i];
  }
  __syncthreads();
  u16* q = (u16*)E + row*4096;
  #pragma unroll
  for (int i = 0; i < 8; i++) q[tid + i*256] = f2bf(t[i]);
  __shared__ float red[256];
  red[tid] = s; __syncthreads();
  for (int w = 128; w > 0; w >>= 1) { if (tid < w) red[tid] += red[tid+w]; __syncthreads(); }
  if (tid == 0) CSI[row] = 1.f/(1e-9f + red[0]);
}

// ---------- apply (MFMA): out[c][m] = xres[c][m] - csi[m]*sum_n xv[c][n]*attnT[m][n] ----------
__global__ __launch_bounds__(512) void apply_mfma_kernel(
    const u16* __restrict__ XV, const u16* __restrict__ AT,
    const float* __restrict__ CSI, const float* __restrict__ XRES, size_t res_bs,
    float* __restrict__ OUT)
{
  int b = blockIdx.z;
  int m0 = blockIdx.x*64;
  const u16* xv = XV + (size_t)b*CCH*NPTS;
  const u16* at = AT + (size_t)b*NPTS*4096;
  int tid = threadIdx.x, lane = tid & 63, w = tid >> 6;
  int wc = (w >> 1)*32, wm = (w & 1)*32;
  int r16 = lane & 15, g4 = lane >> 4;
  f32x4 acc[2][2] = {};
  const u16* pa0 = xv + (size_t)(wc + r16)*NPTS + g4*8;
  const u16* pa1 = pa0 + (size_t)16*NPTS;
  const u16* pb0 = at + (size_t)(m0 + wm + r16)*4096 + g4*8;
  const u16* pb1 = pb0 + (size_t)16*4096;
  for (int k0 = 0; k0 < NPTS; k0 += 32) {
    short8 a0 = ld8(pa0 + k0);
    short8 a1 = ld8(pa1 + k0);
    short8 b0 = ld8(pb0 + k0);
    short8 b1 = ld8(pb1 + k0);
    acc[0][0] = MFMA16(a0, b0, acc[0][0]);
    acc[0][1] = MFMA16(a0, b1, acc[0][1]);
    acc[1][0] = MFMA16(a1, b0, acc[1][0]);
    acc[1][1] = MFMA16(a1, b1, acc[1][1]);
  }
  #pragma unroll
  for (int ca = 0; ca < 2; ca++)
    #pragma unroll
    for (int mb = 0; mb < 2; mb++) {
      int m = m0 + wm + mb*16 + r16;
      float ci = CSI[(size_t)b*NPTS + m];
      #pragma unroll
      for (int j = 0; j < 4; j++) {
        int c = wc + ca*16 + g4*4 + j;
        float v = XRES[(size_t)b*res_bs + (size_t)c*NPTS + m] - acc[ca][mb][j]*ci;
        OUT[((size_t)b*CCH + c)*NPTS + m] = v;
      }
    }
}

// ---------- log_softmax + transpose ----------
__global__ __launch_bounds__(256) void lsm_kernel(const float* __restrict__ Y,
                                                  float* __restrict__ OUT)
{
  int idx = blockIdx.x*256 + threadIdx.x;
  int b = idx >> 11, n = idx & (NPTS-1);
  const float* p = Y + (size_t)b*NCLASS*NPTS + n;
  float m = -3.4e38f;
  #pragma unroll
  for (int k = 0; k < NCLASS; k++) m = fmaxf(m, p[(size_t)k*NPTS]);
  float s = 0.f;
  #pragma unroll
  for (int k = 0; k < NCLASS; k++) s += expf(p[(size_t)k*NPTS] - m);
  float L = m + logf(s);
  float* o = OUT + (size_t)idx*NCLASS;
  #pragma unroll
  for (int k = 0; k < NCLASS; k++) o[k] = p[(size_t)k*NPTS] - L;
}

extern "C" void kernel_launch(void* const* d_in, const int* in_sizes, int n_in,
                              void* d_out, int out_size, void* d_ws, size_t ws_size,
                              hipStream_t stream)
{
  (void)in_sizes; (void)n_in; (void)out_size; (void)ws_size;
  const float* xyz  = (const float*)d_in[0];
  const float* cls  = (const float*)d_in[1];
  const float* Amat = (const float*)d_in[2];
  const float* Bm   = (const float*)d_in[3];
  const float* W1r  = (const float*)d_in[4];
  const float* b1r  = (const float*)d_in[5];
  const float* W1i  = (const float*)d_in[6];
  const float* b1i  = (const float*)d_in[7];
  const float* W2r  = (const float*)d_in[8];
  const float* b2r  = (const float*)d_in[9];
  const float* W2i  = (const float*)d_in[10];
  const float* b2i  = (const float*)d_in[11];
  const float* lbl  = (const float*)d_in[12];
  const float* ftw1 = (const float*)d_in[13];
  const float* ftg1 = (const float*)d_in[14];
  const float* ftb1 = (const float*)d_in[15];
  const float* ftw2 = (const float*)d_in[16];
  const float* ftg2 = (const float*)d_in[17];
  const float* ftb2 = (const float*)d_in[18];
  const float* saqk = (const float*)d_in[19];
  const float* savw = (const float*)d_in[20];
  const float* savb = (const float*)d_in[21];
  const float* satw = (const float*)d_in[22];
  const float* satb = (const float*)d_in[23];
  const float* sag  = (const float*)d_in[24];
  const float* sab  = (const float*)d_in[25];
  const float* fusew= (const float*)d_in[26];
  const float* fuseg= (const float*)d_in[27];
  const float* fuseb= (const float*)d_in[28];
  const float* c1w  = (const float*)d_in[29];
  const float* c1b  = (const float*)d_in[30];
  const float* bn1g = (const float*)d_in[31];
  const float* bn1b = (const float*)d_in[32];
  const float* c2w  = (const float*)d_in[33];
  const float* c2b  = (const float*)d_in[34];
  float* out = (float*)d_out;

  float* ws = (float*)d_ws;
  // R0 region: 33.55M floats (134.2 MB), multi-phase aliased
  const size_t PS  = (size_t)BB*DD*NPTS;   // 4,194,304 u16 per phase plane
  const size_t ISZ = (size_t)BB*DD*DD;     // 524,288 u16 per innT plane
  u16* U = (u16*)ws;
  u16 *ATrh = U+0*PS, *ATrl = U+1*PS, *ATih = U+2*PS, *ATil = U+3*PS;
  u16 *BTrh = U+4*PS, *BTrl = U+5*PS, *BTih = U+6*PS, *BTil = U+7*PS;
  u16 *Bnrh = U+8*PS, *Bnrl = U+9*PS, *Bnih = U+10*PS, *Bnil = U+11*PS;
  u16 *Irh = U+12*PS, *Irl = U+12*PS+ISZ, *Iih = U+12*PS+2*ISZ, *Iil = U+12*PS+3*ISZ;
  float* gsq = (float*)(U + 12*PS + 4*ISZ);          // 16.8 MB, ends < 134 MB
  float2* Gbuf1 = (float2*)ws;                       // aliases eAT (dead by then)
  float2* Gbuf2 = (float2*)(U + 4*PS);               // aliases eBT (dead by then)
  float* E = ws;                                     // SA phase: whole R0
  size_t p = (size_t)BB*NPTS*NPTS;                   // past R0
  float* xfeat = ws + p;  p += (size_t)BB*CCH*NPTS;
  float* feats = ws + p;  p += (size_t)BB*4*CCH*NPTS;
  float* xt1   = ws + p;  p += (size_t)BB*CCH*NPTS;
  float* xt2   = ws + p;  p += (size_t)BB*CCH*NPTS;
  float* ybuf  = ws + p;  p += (size_t)BB*NCLASS*NPTS;
  float* mxv   = ws + p;  p += (size_t)BB*NPTS;
  float* rsv   = ws + p;  p += (size_t)BB*NPTS;
  float* csi   = ws + p;  p += (size_t)BB*NPTS;
  float* rwb   = ws + p;  p += (size_t)BB*DD;
  u16* xqh = (u16*)(ws + p);
  u16* xql = xqh + (size_t)BB*NPTS*32;
  u16* xvb = xql + (size_t)BB*NPTS*32;               // BB*CCH*NPTS u16

  ek1_kernel<<<(int)(PS/256), 256, 0, stream>>>(xyz, Amat, Bm,
      ATrh, ATrl, ATih, ATil, BTrh, BTrl, BTih, BTil);
  ek2_kernel<<<(int)(PS/256), 256, 0, stream>>>(xyz, Bm, Bnrh, Bnrl, Bnih, Bnil);
  inner_mfma_kernel<<<dim3(DD/64, DD/64, BB), 256, 0, stream>>>(
      ATrh, ATrl, ATih, ATil, BTrh, BTrl, BTih, BTil, Irh, Irl, Iih, Iil);
  g_mfma_kernel<<<dim3(DD/64, NPTS/64, BB), 256, 0, stream>>>(
      Bnrh, Bnrl, Bnih, Bnil, Irh, Irl, Iih, Iil, Gbuf1);
  gnorm_kernel<<<BB*NPTS, 256, 0, stream>>>(Gbuf1);
  clinear_mfma_kernel<<<dim3(DD/64, (BB*NPTS)/64), 256, 0, stream>>>(
      Gbuf1, W1r, W1i, b1r, b1i, Gbuf2, 1);
  clinear_mfma_kernel<<<dim3(DD/64, (BB*NPTS)/64), 256, 0, stream>>>(
      Gbuf2, W2r, W2i, b2r, b2i, Gbuf1, 0);
  rw_kernel<<<BB, DD, 0, stream>>>(cls, lbl, rwb);
  gsq_kernel<<<(int)(PS/256), 256, 0, stream>>>(Gbuf1, rwb, gsq);

  sgemm_kernel<<<dim3(NPTS/64, CCH/64, BB), 256, 0, stream>>>(
      ftw1, gsq, xt1, nullptr, nullptr, ftg1, ftb1, nullptr, nullptr, 0,
      CCH, DD, (size_t)DD*NPTS, (size_t)CCH*NPTS, 0, 2|4);
  sgemm_kernel<<<dim3(NPTS/64, CCH/64, BB), 256, 0, stream>>>(
      ftw2, xt1, xfeat, nullptr, nullptr, ftg2, ftb2, nullptr, nullptr, 0,
      CCH, CCH, (size_t)CCH*NPTS, (size_t)CCH*NPTS, 0, 2);

  const float* xsrc = xfeat;
  size_t xbs = (size_t)CCH*NPTS;
  for (int i = 0; i < 4; i++) {
    // q/k projection -> split bf16 xqT [n][32]
    sgemm_kernel<<<dim3(NPTS/64, 1, BB), 256, 0, stream>>>(
        saqk + (size_t)i*32*CCH, xsrc, nullptr, nullptr, nullptr, nullptr, nullptr,
        xqh, xql, 2, 32, CCH, xbs, 0, 0, 0);
    energy_mfma_kernel<<<dim3(NPTS/64, NPTS/64, BB), 256, 0, stream>>>(xqh, xql, E);
    rowstat_kernel<<<BB*NPTS, 256, 0, stream>>>(E, mxv, rsv);
    attnT_kernel<<<BB*NPTS, 256, 0, stream>>>(E, mxv, rsv, csi);
    // xv = vW @ x + vb -> plain bf16 [c][n]
    sgemm_kernel<<<dim3(NPTS/64, CCH/64, BB), 256, 0, stream>>>(
        savw + (size_t)i*CCH*CCH, xsrc, nullptr, nullptr, savb + i*CCH, nullptr, nullptr,
        xvb, nullptr, 1, CCH, CCH, xbs, (size_t)CCH*NPTS, 0, 1);
    apply_mfma_kernel<<<dim3(NPTS/64, 1, BB), 512, 0, stream>>>(
        xvb, (const u16*)E, csi, xsrc, xbs, xt2);
    sgemm_kernel<<<dim3(NPTS/64, CCH/64, BB), 256, 0, stream>>>(
        satw + (size_t)i*CCH*CCH, xt2, feats + (size_t)i*CCH*NPTS, xsrc,
        satb + i*CCH, sag + i*CCH, sab + i*CCH, nullptr, nullptr, 0,
        CCH, CCH, (size_t)CCH*NPTS, (size_t)4*CCH*NPTS, xbs, 1|2|4|8);
    xsrc = feats + (size_t)i*CCH*NPTS;
    xbs = (size_t)4*CCH*NPTS;
  }

  sgemm_kernel<<<dim3(NPTS/64, CCH/64, BB), 256, 0, stream>>>(
      fusew, feats, xt1, nullptr, nullptr, fuseg, fuseb, nullptr, nullptr, 0,
      CCH, 4*CCH, (size_t)4*CCH*NPTS, (size_t)CCH*NPTS, 0, 2|4);
  sgemm_kernel<<<dim3(NPTS/64, CCH/64, BB), 256, 0, stream>>>(
      c1w, xt1, xt2, nullptr, c1b, bn1g, bn1b, nullptr, nullptr, 0,
      CCH, CCH, (size_t)CCH*NPTS, (size_t)CCH*NPTS, 0, 1|2|4);
  sgemm_kernel<<<dim3(NPTS/64, 1, BB), 256, 0, stream>>>(
      c2w, xt2, ybuf, nullptr, c2b, nullptr, nullptr, nullptr, nullptr, 0,
      NCLASS, CCH, (size_t)CCH*NPTS, (size_t)NCLASS*NPTS, 0, 1);
  lsm_kernel<<<(BB*NPTS)/256, 256, 0, stream>>>(ybuf, out);
}